// Round 1
// baseline (541.395 us; speedup 1.0000x reference)
//
#include <hip/hip_runtime.h>

// VectorQuantizer: x[16384][64] fp32, codebook[8192][64] fp32
// out = concat(discrete one-hot [16384][8192] fp32, quantized [16384][64] fp32)
// argmin_k ||x-c_k||^2 == argmax_k (x.c_k - 0.5||c_k||^2)
//
// r13 -> r14: occupancy push. RPB 32->16 (grid 512->1024) so 4 blocks/CU are
// resident under __launch_bounds__(256,4) (16 waves/CU, 4 waves/SIMD) instead
// of 2. Per-wave state halves: one row-group (4 A-frags), one 8-MFMA acc
// chain, 4 argmax slots (~95 VGPR). Total MFMA work unchanged; per-row MFMA
// accumulation order is bit-identical to r13 -> identical scores/argmin.
// Tile loop keeps: depth-2 register prefetch of B-frags + cn2 (issued BEFORE
// the NT zero stores so the vmcnt wait for fragment loads never has to retire
// a slow HBM store), 1 NT f32x4 zero store per thread per tile, in-block
// argmax + one-hot + fused quantized gather.
// Exact fp32 dots via fp16 hi/lo split, 8 MFMA terms, bit-identical order.

#define NROWS 16384
#define KCODES 8192
#define DDIM 64
#define RPB 16                    // rows per block
#define CWAVES 4                  // waves per block (256 threads)
#define WCODES (KCODES / CWAVES)  // 2048 codes per wave
#define WTILES (WCODES / 16)      // 128 tiles per wave

typedef float    f32x4 __attribute__((ext_vector_type(4)));
typedef _Float16 f16x8 __attribute__((ext_vector_type(8)));

// ---------------- kernel 0: fused pack + cn2 ----------------
// thread (Tg, L): code = Tg*16 + (L&15), k-slice = (L>>4)*8 (+32).
// packed[Tg][frag][lane]: frag 0=hi k0..31, 1=hi k32..63, 2=lo k0..31, 3=lo k32..63.
__global__ __launch_bounds__(256) void k_prep(const float* __restrict__ cb,
                                              f16x8* __restrict__ packed,
                                              float* __restrict__ cn2) {
    int tid = blockIdx.x * 256 + threadIdx.x;   // 0..32767
    int Tg = tid >> 6, L = tid & 63;
    int lane15 = L & 15, quad = L >> 4;
    int code = Tg * 16 + lane15;
    const float* p = cb + (size_t)code * DDIM + quad * 8;
    f16x8 h0, l0, h1, l1;
    float s = 0.f;
#pragma unroll
    for (int j = 0; j < 8; ++j) {
        float v = p[j];
        _Float16 h = (_Float16)v;
        h0[j] = h; l0[j] = (_Float16)(v - (float)h);
        s = fmaf(v, v, s);
        float w = p[32 + j];
        _Float16 h2 = (_Float16)w;
        h1[j] = h2; l1[j] = (_Float16)(w - (float)h2);
        s = fmaf(w, w, s);
    }
    s += __shfl_xor(s, 16, 64);
    s += __shfl_xor(s, 32, 64);
    if (quad == 0) cn2[code] = 0.5f * s;
    f16x8* out = packed + (size_t)Tg * 256 + L;
    out[0]   = h0;
    out[64]  = h1;
    out[128] = l0;
    out[192] = l1;
}

// ---------------- kernel 1: MFMA + argmax + NT zero-fill + one-hot + quantized ----------------
__global__ __launch_bounds__(256, 4) void k_main(const float* __restrict__ x,
                                                 const float* __restrict__ cb,
                                                 const f16x8* __restrict__ packed,
                                                 const float* __restrict__ cn2,
                                                 float* __restrict__ discrete,
                                                 float* __restrict__ quantized) {
    const int t = threadIdx.x;
    const int L = t & 63;
    const int w = t >> 6;                 // wave = code quarter (ascending codes)
    const int row0 = blockIdx.x * RPB;
    const int lane15 = L & 15;
    const int quad = L >> 4;

    // ---- A fragments: one row group of 16, exact hi/lo split ----
    const float* xa = x + (size_t)(row0 + lane15) * DDIM + quad * 8;
    f16x8 Ah0, Al0, Ah1, Al1;
#pragma unroll
    for (int j = 0; j < 8; ++j) {
        float v = xa[j];        _Float16 h = (_Float16)v;
        Ah0[j] = h; Al0[j] = (_Float16)(v - (float)h);
        v = xa[32 + j];         h = (_Float16)v;
        Ah1[j] = h; Al1[j] = (_Float16)(v - (float)h);
    }

    float bv[4];
    int   bi[4];
#pragma unroll
    for (int r = 0; r < 4; ++r) { bv[r] = -3.4e38f; bi[r] = 0; }

    const f32x4 zero4 = {0.f, 0.f, 0.f, 0.f};
    const int code0 = w * WCODES;
    const f16x8* pbase = packed + (size_t)(code0 >> 4) * 256 + L;
    const float* cnp = cn2 + code0 + lane15;

    // preload tiles 0 (cur) and 1 (nxt): B frags + cn
    f16x8 ch0 = pbase[0], ch1 = pbase[64], cl0 = pbase[128], cl1 = pbase[192];
    float cn = cnp[0];
    const f16x8* p1 = pbase + 256;
    f16x8 nh0 = p1[0], nh1 = p1[64], nl0 = p1[128], nl1 = p1[192];
    float cnn = cnp[16];

    f32x4* zdst = (f32x4*)(discrete + (size_t)row0 * KCODES);   // 32768 f32x4/block

    for (int i = 0; i < WTILES; ++i) {
        // ---- prefetch tile i+2 FIRST (loads precede stores so the fragment
        //      waitcnt never has to retire an NT HBM store) ----
        const int i2 = (i + 2 < WTILES) ? i + 2 : WTILES - 1;
        const f16x8* pm = pbase + (size_t)i2 * 256;
        f16x8 mh0 = pm[0], mh1 = pm[64], ml0 = pm[128], ml1 = pm[192];
        float cnm = cnp[i2 * 16];

        // ---- NT zero-fill: 1 f32x4 per thread per tile (32768 total/block) ----
        __builtin_nontemporal_store(zero4, zdst + i * 256 + t);

        // ---- compute current tile (order identical to r13's accA chain) ----
        f32x4 acc = {-cn, -cn, -cn, -cn};
        acc = __builtin_amdgcn_mfma_f32_16x16x32_f16(Ah0, ch0, acc, 0, 0, 0);
        acc = __builtin_amdgcn_mfma_f32_16x16x32_f16(Ah1, ch1, acc, 0, 0, 0);
        acc = __builtin_amdgcn_mfma_f32_16x16x32_f16(Al0, ch0, acc, 0, 0, 0);
        acc = __builtin_amdgcn_mfma_f32_16x16x32_f16(Al1, ch1, acc, 0, 0, 0);
        acc = __builtin_amdgcn_mfma_f32_16x16x32_f16(Ah0, cl0, acc, 0, 0, 0);
        acc = __builtin_amdgcn_mfma_f32_16x16x32_f16(Ah1, cl1, acc, 0, 0, 0);
        acc = __builtin_amdgcn_mfma_f32_16x16x32_f16(Al0, cl0, acc, 0, 0, 0);
        acc = __builtin_amdgcn_mfma_f32_16x16x32_f16(Al1, cl1, acc, 0, 0, 0);

        const int vcode = code0 + i * 16 + lane15;
#pragma unroll
        for (int r = 0; r < 4; ++r) {
            if (acc[r] > bv[r]) { bv[r] = acc[r]; bi[r] = vcode; }
        }

        // ---- rotate pipeline stages ----
        ch0 = nh0; ch1 = nh1; cl0 = nl0; cl1 = nl1; cn = cnn;
        nh0 = mh0; nh1 = mh1; nl0 = ml0; nl1 = ml1; cnn = cnm;
    }

    // ---- 16-lane butterfly per quad, then cross-wave LDS reduce ----
    __shared__ float rv[RPB][CWAVES + 1];
    __shared__ int   ri[RPB][CWAVES + 1];
    __shared__ int   sidx[RPB];
#pragma unroll
    for (int r = 0; r < 4; ++r) {
        float v = bv[r];
        int  id = bi[r];
#pragma unroll
        for (int m = 1; m < 16; m <<= 1) {
            float ov = __shfl_xor(v, m, 64); int oi = __shfl_xor(id, m, 64);
            if (ov > v || (ov == v && oi < id)) { v = ov; id = oi; }
        }
        if (lane15 == 0) {
            rv[quad * 4 + r][w] = v;
            ri[quad * 4 + r][w] = id;
        }
    }
    __syncthreads();   // drains NT zero stores before the 1.0 write
    if (t < RPB) {
        float bvv = rv[t][0];
        int   bii = ri[t][0];
#pragma unroll
        for (int w2 = 1; w2 < CWAVES; ++w2) {  // ascending wave = ascending codes
            float vv = rv[t][w2];
            int  ii = ri[t][w2];
            if (vv > bvv || (vv == bvv && ii < bii)) { bvv = vv; bii = ii; }
        }
        sidx[t] = bii;
        discrete[(size_t)(row0 + t) * KCODES + bii] = 1.0f;
    }
    __syncthreads();

    // ---- fused quantized gather: 16 rows x 16 float4, one per thread ----
    {
        int r = t >> 4, c = t & 15;
        float4 vq = *((const float4*)(cb + (size_t)sidx[r] * DDIM) + c);
        *((float4*)(quantized + (size_t)(row0 + r) * DDIM) + c) = vq;
    }
}

extern "C" void kernel_launch(void* const* d_in, const int* in_sizes, int n_in,
                              void* d_out, int out_size, void* d_ws, size_t ws_size,
                              hipStream_t stream) {
    const float* x  = (const float*)d_in[0];   // 16*32*32*64
    const float* cb = (const float*)d_in[1];   // 8192*64

    float* discrete  = (float*)d_out;                          // 16384*8192
    float* quantized = (float*)d_out + (size_t)NROWS * KCODES; // 16384*64

    // workspace layout: cn2 (32 KB) | packed B-frags (2 MB).
    float* cn2    = (float*)d_ws;              // 8192 floats
    f16x8* packed = (f16x8*)(cn2 + KCODES);    // 2 MB

    k_prep<<<(KCODES / 16) * 64 / 256, 256, 0, stream>>>(cb, packed, cn2);
    k_main<<<NROWS / RPB, CWAVES * 64, 0, stream>>>(x, cb, packed, cn2,
                                                    discrete, quantized);
}